// Round 2
// baseline (69.753 us; speedup 1.0000x reference)
//
#include <hip/hip_runtime.h>

// Problem constants (from reference): B=8, N=4096, D=3
#define B_ 8
#define N_ 4096
#define P_ 2                          // own points per lane
#define OWN_PER_BLOCK (64 * P_)       // 128
#define CHUNKS (N_ / OWN_PER_BLOCK)   // 32

__global__ void chamfer_init_acc(double* acc) {
    if (threadIdx.x < 2) acc[threadIdx.x] = 0.0;
}

// dir 0: own = y (j), opp = x, mask = x_mask -> acc[0]   (min over axis 1)
// dir 1: own = x (i), opp = y, mask = y_mask -> acc[1]   (min over axis 2)
// Block: 256 threads = 4 waves. Block owns 128 own-points (lane l holds 2:
// base + p*64 + l). Wave s scans opposite range [s*1024, (s+1)*1024).
// Opposite coordinates are wave-uniform -> scalar (SMEM) loads, zero LDS
// traffic in the hot loop; distances consume SGPR operands directly.
__global__ __launch_bounds__(256) void chamfer_min_kernel(
        const float* __restrict__ x, const float* __restrict__ y,
        const float* __restrict__ xm, const float* __restrict__ ym,
        double* __restrict__ acc) {
    const int dir  = blockIdx.z;
    const int b    = blockIdx.y;
    const int base = blockIdx.x * OWN_PER_BLOCK;

    const float* own = dir ? x  : y;
    const float* opp = dir ? y  : x;
    const float* msk = dir ? ym : xm;

    const int t = threadIdx.x;
    const int l = t & 63;
    const int s = t >> 6;

    // Per-lane own points (12 B/lane, coalesced).
    float px[P_], py[P_], pz[P_];
#pragma unroll
    for (int p = 0; p < P_; ++p) {
        const float* op = own + ((size_t)b * N_ + base + p * 64 + l) * 3;
        px[p] = op[0]; py[p] = op[1]; pz[p] = op[2];
    }

    float m[P_][4];
#pragma unroll
    for (int p = 0; p < P_; ++p)
#pragma unroll
        for (int c = 0; c < 4; ++c) m[p][c] = 1e30f;

    const float* ob = opp + (size_t)b * N_ * 3;
    const int kbeg = s * (N_ / 4);
    const int kend = kbeg + (N_ / 4);

#pragma unroll 2
    for (int k = kbeg; k < kend; k += 4) {
        // 4 opposite points = 12 consecutive floats, wave-uniform address.
        const float* q = ob + (size_t)k * 3;
        const float q0 = q[0],  q1 = q[1],  q2  = q[2],  q3  = q[3];
        const float q4 = q[4],  q5 = q[5],  q6  = q[6],  q7  = q[7];
        const float q8 = q[8],  q9 = q[9],  q10 = q[10], q11 = q[11];
#pragma unroll
        for (int p = 0; p < P_; ++p) {
            { float dx = q0 - px[p], dy = q1  - py[p], dz = q2  - pz[p];
              float d = dx*dx + dy*dy + dz*dz; m[p][0] = fminf(m[p][0], d); }
            { float dx = q3 - px[p], dy = q4  - py[p], dz = q5  - pz[p];
              float d = dx*dx + dy*dy + dz*dz; m[p][1] = fminf(m[p][1], d); }
            { float dx = q6 - px[p], dy = q7  - py[p], dz = q8  - pz[p];
              float d = dx*dx + dy*dy + dz*dz; m[p][2] = fminf(m[p][2], d); }
            { float dx = q9 - px[p], dy = q10 - py[p], dz = q11 - pz[p];
              float d = dx*dx + dy*dy + dz*dz; m[p][3] = fminf(m[p][3], d); }
        }
    }

    // Cross-wave min reduction (tiny LDS buffer only).
    __shared__ float red[4][OWN_PER_BLOCK];
#pragma unroll
    for (int p = 0; p < P_; ++p)
        red[s][p * 64 + l] = fminf(fminf(m[p][0], m[p][1]), fminf(m[p][2], m[p][3]));
    __syncthreads();

    if (t < OWN_PER_BLOCK) {
        float mn = fminf(fminf(red[0][t], red[1][t]), fminf(red[2][t], red[3][t]));
        float w  = msk[(size_t)b * N_ + base + t];
        double val = (double)(w * mn);
        for (int off = 32; off; off >>= 1)
            val += __shfl_down(val, off);
        if (l == 0)
            atomicAdd(&acc[dir], val);
    }
}

__global__ void chamfer_finalize(const double* __restrict__ acc, float* __restrict__ out) {
    double d = (acc[0] - acc[1]) / (double)(B_ * N_);
    out[0] = (float)(d * d);
}

extern "C" void kernel_launch(void* const* d_in, const int* in_sizes, int n_in,
                              void* d_out, int out_size, void* d_ws, size_t ws_size,
                              hipStream_t stream) {
    const float* x  = (const float*)d_in[0];
    const float* y  = (const float*)d_in[1];
    const float* xm = (const float*)d_in[2];
    const float* ym = (const float*)d_in[3];
    float* out = (float*)d_out;
    double* acc = (double*)d_ws;   // 2 doubles of scratch

    chamfer_init_acc<<<1, 64, 0, stream>>>(acc);

    dim3 grid(CHUNKS, B_, 2);   // 32 x 8 x 2 = 512 blocks
    chamfer_min_kernel<<<grid, 256, 0, stream>>>(x, y, xm, ym, acc);

    chamfer_finalize<<<1, 1, 0, stream>>>(acc, out);
}